// Round 8
// baseline (3536.091 us; speedup 1.0000x reference)
//
#include <hip/hip_runtime.h>

typedef unsigned short u16;
typedef unsigned int   u32;
typedef __bf16 bf16x8 __attribute__((ext_vector_type(8)));
typedef float  f32x4  __attribute__((ext_vector_type(4)));
typedef u32    u32x2  __attribute__((ext_vector_type(2)));

#define DIMD  256
#define DIMH  512
#define MTILE 32
#define NTHREADS 512

// LDS (u16 units): double-buffered h tile + k2f (K2 park). x-tile aliases k2f.
#define HSTR 520                       // 512 + 8 pad
#define USTR 264                       // 256 + 8 pad (x tile, prologue only)
#define H0_BASE 0
#define H1_BASE (32*HSTR)              // 16640
#define K2F_BASE (2*32*HSTR)           // 33280 u16 = byte 66560 (4B aligned)
#define LDS_U16 (K2F_BASE + 16384)     // + 16*512 u32 = 32768B -> 99328 B total

#define DT 0.0625f

__device__ __forceinline__ u16 f2bf(float f) {          // RNE fp32->bf16
  u32 u = __float_as_uint(f);
  u += 0x7FFFu + ((u >> 16) & 1u);
  return (u16)(u >> 16);
}
__device__ __forceinline__ u32 pk(float a, float b) {
#if __has_builtin(__builtin_amdgcn_cvt_pk_bf16_f32)
  auto v = __builtin_amdgcn_cvt_pk_bf16_f32(a, b);      // v_cvt_pk_bf16_f32 (RNE)
  u32 r; __builtin_memcpy(&r, &v, 4); return r;
#else
  return (u32)f2bf(a) | ((u32)f2bf(b) << 16);
#endif
}
__device__ __forceinline__ float bflo(u32 p) { return __uint_as_float(p << 16); }
__device__ __forceinline__ float bfhi(u32 p) { return __uint_as_float(p & 0xFFFF0000u); }
__device__ __forceinline__ float tanh_fast(float x) {
  float e = __builtin_amdgcn_exp2f(x * 2.8853900817779268f);  // 2*log2(e)
  return 1.0f - 2.0f * __builtin_amdgcn_rcpf(e + 1.0f);
}

// Barrier draining ONLY LDS ops (lgkmcnt); global weight prefetches survive.
// 0xC07F = vmcnt(63) expcnt(7) lgkmcnt(0).
__device__ __forceinline__ void bar_lds() {
  asm volatile("" ::: "memory");
  __builtin_amdgcn_s_waitcnt(0xC07F);
  __builtin_amdgcn_s_barrier();
  asm volatile("" ::: "memory");
}

// ---------------- precompute kernels ----------------
// w1t bf16 [n=512][k=256] = W1[k][n]
__global__ void convert_w1(const float* __restrict__ W1, u16* __restrict__ w1t) {
  int idx = blockIdx.x * 256 + threadIdx.x;   // 512 blocks
  int n = idx >> 8, k = idx & 255;
  w1t[idx] = f2bf(W1[k * DIMH + n]);
}

// Gt bf16 [n=512][j=512] = G[j][n], G = W2@W1 (fp32 dot, rounded once).
// Orientation: j uniform per block (W2 row broadcast), n coalesced (W1 reads).
__global__ void make_gt(const float* __restrict__ W1, const float* __restrict__ W2,
                        u16* __restrict__ gt) {
  int t = blockIdx.x * 256 + threadIdx.x;     // 1024 blocks -> 262144
  int j = t >> 9, n = t & 511;
  float s = 0.f;
#pragma unroll 4
  for (int d = 0; d < 256; ++d)
    s += W2[j * DIMD + d] * W1[d * DIMH + n];
  gt[n * DIMH + j] = f2bf(s);
}

// g0[n] = b2@W1 ; w2f[j] = W2@Wfc ; b2f = b2.Wfc   (1 block x 512)
__global__ void make_aux(const float* __restrict__ W1, const float* __restrict__ W2,
                         const float* __restrict__ b2, const float* __restrict__ wfc,
                         float* __restrict__ g0, float* __restrict__ w2f,
                         float* __restrict__ b2f) {
  int t = threadIdx.x;
  {
    float s = 0.f;
    for (int d = 0; d < 256; ++d) s += b2[d] * W1[d * DIMH + t];
    g0[t] = s;
  }
  {
    float s = 0.f;
    for (int d = 0; d < 256; ++d) s += W2[t * DIMD + d] * wfc[d];
    w2f[t] = s;
  }
  if (t < 64) {
    float s = 0.f;
    for (int d = t; d < 256; d += 64) s += b2[d] * wfc[d];
    s += __shfl_xor(s, 1);  s += __shfl_xor(s, 2);  s += __shfl_xor(s, 4);
    s += __shfl_xor(s, 8);  s += __shfl_xor(s, 16); s += __shfl_xor(s, 32);
    if (t == 0) b2f[0] = s;
  }
}

// f0[row] = x[row,:].Wfc  (wave per row; 4096 blocks x 256)
__global__ void make_f0(const float* __restrict__ x, const float* __restrict__ wfc,
                        float* __restrict__ f0) {
  int row  = blockIdx.x * 4 + (threadIdx.x >> 6);
  int lane = threadIdx.x & 63;
  float s = 0.f;
#pragma unroll
  for (int d = lane; d < 256; d += 64) s += x[row * DIMD + d] * wfc[d];
  s += __shfl_xor(s, 1);  s += __shfl_xor(s, 2);  s += __shfl_xor(s, 4);
  s += __shfl_xor(s, 8);  s += __shfl_xor(s, 16); s += __shfl_xor(s, 32);
  if (lane == 0) f0[row] = s;
}

__device__ __forceinline__ void mfma_g(f32x4 (&acc)[4][2],
                                       const bf16x8 (&a)[4], const bf16x8 (&b)[2]) {
#pragma unroll
  for (int mb = 0; mb < 4; ++mb)
#pragma unroll
    for (int nb = 0; nb < 2; ++nb)
      acc[mb][nb] = __builtin_amdgcn_mfma_f32_16x16x32_bf16(a[mb], b[nb], acc[mb][nb], 0, 0, 0);
}

// P-space ODE: P_y = y@W1 (fp32 anchor, 32/thread). Per stage: ONE GEMM
// K_s = h_s@G (K=512, 128 MFMA/wave) -> fused epilogue computes next
// pre-activation combo, tanh, h-write (double-buffered LDS), and the
// out-scalar partial gp += dt*b_j*(h_j.w2f). ONE barrier per stage.
// MTILE=32, 8 waves, 2 waves/SIMD: ~200 VGPR + 32 AGPR < 256 unified.
__global__ __attribute__((amdgpu_flat_work_group_size(NTHREADS, NTHREADS),
                          amdgpu_waves_per_eu(2, 2)))
void ode_fused(
    const float* __restrict__ x,   const float* __restrict__ b1,
    const float* __restrict__ bfc, const u16* __restrict__ w1t,
    const u16* __restrict__ gt,    const float* __restrict__ g0,
    const float* __restrict__ w2f, const float* __restrict__ b2f,
    const float* __restrict__ f0,  float* __restrict__ out)
{
  __shared__ u16 lds[LDS_U16];
  u32* k2f = (u32*)&lds[K2F_BASE];       // 16 u32/thread K2 park
  u16* xtile = &lds[K2F_BASE];           // prologue-only alias (16.9KB < 32KB)

  const int tid   = threadIdx.x;
  const int wg    = blockIdx.x;
  const int wv    = tid >> 6;            // wave 0..7
  const int lane  = tid & 63;
  const int lanel = lane & 15;
  const int laneq = lane >> 4;

  // h tile pointers (double buffer)
  const u16* rd0 = &lds[H0_BASE + lanel * HSTR + laneq * 8];
  const u16* rd1 = &lds[H1_BASE + lanel * HSTR + laneq * 8];
  u16* wr0 = &lds[H0_BASE + lanel * HSTR + wv * 64 + laneq * 4];
  u16* wr1 = &lds[H1_BASE + lanel * HSTR + wv * 64 + laneq * 4];

  // Thread owns fragments (col = wv*64 + mb*16 + laneq*4 + r, row = nb*16+lanel)
  //   flat i = mb*8 + nb*4 + r (P_y[32]); packed pair p = mb*4 + nb*2 + (r>>1)

  u32 b1p[8], g0p[8];
  float w2fv[16];
#pragma unroll
  for (int mb = 0; mb < 4; ++mb) {
    int base = wv * 64 + mb * 16 + laneq * 4;
    b1p[mb * 2 + 0] = pk(b1[base + 0], b1[base + 1]);
    b1p[mb * 2 + 1] = pk(b1[base + 2], b1[base + 3]);
    g0p[mb * 2 + 0] = pk(g0[base + 0], g0[base + 1]);
    g0p[mb * 2 + 1] = pk(g0[base + 2], g0[base + 3]);
    const float4 wv4 = *(const float4*)&w2f[base];
    w2fv[mb * 4 + 0] = wv4.x; w2fv[mb * 4 + 1] = wv4.y;
    w2fv[mb * 4 + 2] = wv4.z; w2fv[mb * 4 + 3] = wv4.w;
  }

  // stage x -> LDS (bf16), 32 rows x 256 cols
#pragma unroll
  for (int nb = 0; nb < 2; ++nb)
#pragma unroll
    for (int mb = 0; mb < 2; ++mb) {
      const float4 v = *(const float4*)&x[(wg * MTILE + nb * 16 + lanel) * DIMD +
                                          wv * 32 + mb * 16 + laneq * 4];
      u32x2 w; w.x = pk(v.x, v.y); w.y = pk(v.z, v.w);
      *(u32x2*)(&xtile[lanel * USTR + wv * 32 + laneq * 4] + nb * 16 * USTR + mb * 16) = w;
    }

  const u16* w1b[4];
  const u16* gbase[4];
#pragma unroll
  for (int mb = 0; mb < 4; ++mb) {
    int n = wv * 64 + mb * 16 + lanel;
    w1b[mb]   = w1t + n * DIMD + laneq * 8;
    gbase[mb] = gt  + n * DIMH + laneq * 8;
  }
  const u16* xRd = &xtile[lanel * USTR + laneq * 8];

  auto ldW1 = [&](bf16x8 (&a)[4], int kk) {
#pragma unroll
    for (int mb = 0; mb < 4; ++mb) a[mb] = *(const bf16x8*)(w1b[mb] + kk * 32);
  };
  auto ldGt = [&](bf16x8 (&a)[4], int kk) {
#pragma unroll
    for (int mb = 0; mb < 4; ++mb) a[mb] = *(const bf16x8*)(gbase[mb] + kk * 32);
  };
  auto ldX = [&](bf16x8 (&b)[2], int kk) {
#pragma unroll
    for (int nb = 0; nb < 2; ++nb) b[nb] = *(const bf16x8*)(xRd + nb * 16 * USTR + kk * 32);
  };
  auto ldH = [&](bf16x8 (&b)[2], const u16* base, int kk) {
#pragma unroll
    for (int nb = 0; nb < 2; ++nb) b[nb] = *(const bf16x8*)(base + nb * 16 * HSTR + kk * 32);
  };

  float Py[32];            // fp32 anchor (y@W1)
  u32 st[32];              // [0:16) K1 then u6-delta; [16:32) K3 (bf16 pairs)
  float gp0 = 0.f, gp1 = 0.f;   // out-scalar partials (row nb=0 / nb=1)
  bf16x8 aP[4];            // cross-barrier A (weights) kk=0 prefetch

  // gp coefficients (dt*b_j) and RK constants
  const float GB1 = DT * (float)(35.0/384.0);
  const float GB3 = DT * (float)(500.0/1113.0);
  const float GB4 = DT * (float)(125.0/192.0);
  const float GB5 = DT * (float)(-2187.0/6784.0);
  const float GB6 = DT * (float)(11.0/84.0);

  // ---------------- prologue: P0 = x@W1 ; h1 = tanh(P0+b1) ----------------
  {
    bf16x8 aA[4], aB[4], bA[2], bB[2];
    ldW1(aA, 0);
    bar_lds();                       // x tile visible
    f32x4 acc[4][2];
#pragma unroll
    for (int mb = 0; mb < 4; ++mb)
#pragma unroll
      for (int nb = 0; nb < 2; ++nb) acc[mb][nb] = (f32x4){0.f, 0.f, 0.f, 0.f};
    ldX(bA, 0);
#pragma unroll 1
    for (int kk2 = 0; kk2 < 3; ++kk2) {
      ldW1(aB, 2 * kk2 + 1); ldX(bB, 2 * kk2 + 1);
      mfma_g(acc, aA, bA);
      ldW1(aA, 2 * kk2 + 2); ldX(bA, 2 * kk2 + 2);
      mfma_g(acc, aB, bB);
    }
    ldW1(aB, 7); ldX(bB, 7);
    mfma_g(acc, aA, bA);
    ldGt(aP, 0);                     // steady-state kk=0 prefetch
    mfma_g(acc, aB, bB);

    float ts0 = 0.f, ts1 = 0.f;
#pragma unroll
    for (int mb = 0; mb < 4; ++mb)
#pragma unroll
      for (int nb = 0; nb < 2; ++nb) {
        int i = mb * 8 + nb * 4;
        Py[i + 0] = acc[mb][nb][0]; Py[i + 1] = acc[mb][nb][1];
        Py[i + 2] = acc[mb][nb][2]; Py[i + 3] = acc[mb][nb][3];
        float h0 = tanh_fast(Py[i + 0] + bflo(b1p[mb * 2 + 0]));
        float h1 = tanh_fast(Py[i + 1] + bfhi(b1p[mb * 2 + 0]));
        float h2 = tanh_fast(Py[i + 2] + bflo(b1p[mb * 2 + 1]));
        float h3 = tanh_fast(Py[i + 3] + bfhi(b1p[mb * 2 + 1]));
        u32x2 w; w.x = pk(h0, h1); w.y = pk(h2, h3);
        *(u32x2*)(wr0 + nb * 16 * HSTR + mb * 16) = w;
        float part = h0 * w2fv[mb * 4 + 0] + h1 * w2fv[mb * 4 + 1] +
                     h2 * w2fv[mb * 4 + 2] + h3 * w2fv[mb * 4 + 3];
        if (nb == 0) ts0 += part; else ts1 += part;
      }
    gp0 = GB1 * ts0; gp1 = GB1 * ts1;
    bar_lds();                       // h1 (buf0) visible; aP in flight
  }

  const u16* rdC = rd0; const u16* rdO = rd1;
  u16* wrC = wr1; u16* wrO = wr0;    // region reads cur buf, writes other

#pragma unroll 1
  for (int step = 0; step < 16; ++step) {
#pragma unroll 1
    for (int s = 1; s <= 6; ++s) {
      // ---------- GEMM: K_s[col][row] = Gt(A,global) x h_s(B,LDS), K=512 ----
      f32x4 acc[4][2];
#pragma unroll
      for (int mb = 0; mb < 4; ++mb)
#pragma unroll
        for (int nb = 0; nb < 2; ++nb) acc[mb][nb] = (f32x4){0.f, 0.f, 0.f, 0.f};
      bf16x8 aA[4], aB[4], bA[2], bB[2];
#pragma unroll
      for (int mb = 0; mb < 4; ++mb) aA[mb] = aP[mb];
      ldH(bA, rdC, 0);
#pragma unroll 1
      for (int kk2 = 0; kk2 < 7; ++kk2) {
        ldGt(aB, 2 * kk2 + 1); ldH(bB, rdC, 2 * kk2 + 1);
        mfma_g(acc, aA, bA);
        ldGt(aA, 2 * kk2 + 2); ldH(bA, rdC, 2 * kk2 + 2);
        mfma_g(acc, aB, bB);
      }
      ldGt(aB, 15); ldH(bB, rdC, 15);
      mfma_g(acc, aA, bA);
      ldGt(aP, 0);                   // next region kk=0 prefetch (survives bar)
      mfma_g(acc, aB, bB);

      // ---------- fused epilogue: K_s -> P-combo -> h_{s+1} -> write+gp ----
      float ts0 = 0.f, ts1 = 0.f;
      if (s == 1) {
        const float C = DT * 0.2f;
#pragma unroll
        for (int mb = 0; mb < 4; ++mb)
#pragma unroll
          for (int nb = 0; nb < 2; ++nb) {
            int i = mb * 8 + nb * 4, p = mb * 4 + nb * 2;
            float Ka = acc[mb][nb][0] + bflo(g0p[mb * 2 + 0]);
            float Kb = acc[mb][nb][1] + bfhi(g0p[mb * 2 + 0]);
            float Kc = acc[mb][nb][2] + bflo(g0p[mb * 2 + 1]);
            float Kd = acc[mb][nb][3] + bfhi(g0p[mb * 2 + 1]);
            st[p] = pk(Ka, Kb); st[p + 1] = pk(Kc, Kd);
            float h0 = tanh_fast(Py[i + 0] + C * Ka + bflo(b1p[mb * 2 + 0]));
            float h1 = tanh_fast(Py[i + 1] + C * Kb + bfhi(b1p[mb * 2 + 0]));
            float h2 = tanh_fast(Py[i + 2] + C * Kc + bflo(b1p[mb * 2 + 1]));
            float h3 = tanh_fast(Py[i + 3] + C * Kd + bfhi(b1p[mb * 2 + 1]));
            u32x2 w; w.x = pk(h0, h1); w.y = pk(h2, h3);
            *(u32x2*)(wrC + nb * 16 * HSTR + mb * 16) = w;
            // b2 = 0: no gp for h2
          }
      } else if (s == 2) {
        const float C1 = DT * 0.075f, C2 = DT * 0.225f;
#pragma unroll
        for (int mb = 0; mb < 4; ++mb)
#pragma unroll
          for (int nb = 0; nb < 2; ++nb) {
            int i = mb * 8 + nb * 4, p = mb * 4 + nb * 2;
            float Ka = acc[mb][nb][0] + bflo(g0p[mb * 2 + 0]);
            float Kb = acc[mb][nb][1] + bfhi(g0p[mb * 2 + 0]);
            float Kc = acc[mb][nb][2] + bflo(g0p[mb * 2 + 1]);
            float Kd = acc[mb][nb][3] + bfhi(g0p[mb * 2 + 1]);
            k2f[p * NTHREADS + tid]       = pk(Ka, Kb);   // park K2
            k2f[(p + 1) * NTHREADS + tid] = pk(Kc, Kd);
            float h0 = tanh_fast(Py[i + 0] + C1 * bflo(st[p])     + C2 * Ka + bflo(b1p[mb * 2 + 0]));
            float h1 = tanh_fast(Py[i + 1] + C1 * bfhi(st[p])     + C2 * Kb + bfhi(b1p[mb * 2 + 0]));
            float h2 = tanh_fast(Py[i + 2] + C1 * bflo(st[p + 1]) + C2 * Kc + bflo(b1p[mb * 2 + 1]));
            float h3 = tanh_fast(Py[i + 3] + C1 * bfhi(st[p + 1]) + C2 * Kd + bfhi(b1p[mb * 2 + 1]));
            u32x2 w; w.x = pk(h0, h1); w.y = pk(h2, h3);
            *(u32x2*)(wrC + nb * 16 * HSTR + mb * 16) = w;
            float part = h0 * w2fv[mb * 4 + 0] + h1 * w2fv[mb * 4 + 1] +
                         h2 * w2fv[mb * 4 + 2] + h3 * w2fv[mb * 4 + 3];
            if (nb == 0) ts0 += part; else ts1 += part;
          }
        gp0 += GB3 * ts0; gp1 += GB3 * ts1;
      } else if (s == 3) {
        const float C1 = DT * (float)(44.0/45.0);
        const float C2 = DT * (float)(-56.0/15.0);
        const float C3 = DT * (float)(32.0/9.0);
#pragma unroll
        for (int mb = 0; mb < 4; ++mb)
#pragma unroll
          for (int nb = 0; nb < 2; ++nb) {
            int i = mb * 8 + nb * 4, p = mb * 4 + nb * 2;
            float Ka = acc[mb][nb][0] + bflo(g0p[mb * 2 + 0]);
            float Kb = acc[mb][nb][1] + bfhi(g0p[mb * 2 + 0]);
            float Kc = acc[mb][nb][2] + bflo(g0p[mb * 2 + 1]);
            float Kd = acc[mb][nb][3] + bfhi(g0p[mb * 2 + 1]);
            st[16 + p] = pk(Ka, Kb); st[16 + p + 1] = pk(Kc, Kd);
            u32 q0 = k2f[p * NTHREADS + tid], q1 = k2f[(p + 1) * NTHREADS + tid];
            float h0 = tanh_fast(Py[i + 0] + C1 * bflo(st[p])     + C2 * bflo(q0) + C3 * Ka + bflo(b1p[mb * 2 + 0]));
            float h1 = tanh_fast(Py[i + 1] + C1 * bfhi(st[p])     + C2 * bfhi(q0) + C3 * Kb + bfhi(b1p[mb * 2 + 0]));
            float h2 = tanh_fast(Py[i + 2] + C1 * bflo(st[p + 1]) + C2 * bflo(q1) + C3 * Kc + bflo(b1p[mb * 2 + 1]));
            float h3 = tanh_fast(Py[i + 3] + C1 * bfhi(st[p + 1]) + C2 * bfhi(q1) + C3 * Kd + bfhi(b1p[mb * 2 + 1]));
            u32x2 w; w.x = pk(h0, h1); w.y = pk(h2, h3);
            *(u32x2*)(wrC + nb * 16 * HSTR + mb * 16) = w;
            float part = h0 * w2fv[mb * 4 + 0] + h1 * w2fv[mb * 4 + 1] +
                         h2 * w2fv[mb * 4 + 2] + h3 * w2fv[mb * 4 + 3];
            if (nb == 0) ts0 += part; else ts1 += part;
          }
        gp0 += GB4 * ts0; gp1 += GB4 * ts1;
      } else if (s == 4) {
        // P5; fold K1..K4 into u6-delta and Py; K1..K3 die here
        const float C51 = DT * (float)(19372.0/6561.0);
        const float C52 = DT * (float)(-25360.0/2187.0);
        const float C53 = DT * (float)(64448.0/6561.0);
        const float C54 = DT * (float)(-212.0/729.0);
        const float D61 = DT * (float)(9017.0/3168.0  - 35.0/384.0);
        const float D62 = DT * (float)(-355.0/33.0);
        const float D63 = DT * (float)(46732.0/5247.0 - 500.0/1113.0);
        const float D64 = DT * (float)(49.0/176.0     - 125.0/192.0);
        const float E1  = DT * (float)(35.0/384.0);
        const float E3  = DT * (float)(500.0/1113.0);
        const float E4  = DT * (float)(125.0/192.0);
#pragma unroll
        for (int mb = 0; mb < 4; ++mb)
#pragma unroll
          for (int nb = 0; nb < 2; ++nb) {
            int i = mb * 8 + nb * 4, p = mb * 4 + nb * 2;
            float K40 = acc[mb][nb][0] + bflo(g0p[mb * 2 + 0]);
            float K41 = acc[mb][nb][1] + bfhi(g0p[mb * 2 + 0]);
            float K42 = acc[mb][nb][2] + bflo(g0p[mb * 2 + 1]);
            float K43 = acc[mb][nb][3] + bfhi(g0p[mb * 2 + 1]);
            float K10 = bflo(st[p]),      K11 = bfhi(st[p]);
            float K12 = bflo(st[p + 1]),  K13 = bfhi(st[p + 1]);
            u32 q0 = k2f[p * NTHREADS + tid], q1 = k2f[(p + 1) * NTHREADS + tid];
            float K20 = bflo(q0), K21 = bfhi(q0);
            float K22 = bflo(q1), K23 = bfhi(q1);
            float K30 = bflo(st[16 + p]),     K31 = bfhi(st[16 + p]);
            float K32 = bflo(st[16 + p + 1]), K33 = bfhi(st[16 + p + 1]);
            float h0 = tanh_fast(Py[i + 0] + C51 * K10 + C52 * K20 + C53 * K30 + C54 * K40 + bflo(b1p[mb * 2 + 0]));
            float h1 = tanh_fast(Py[i + 1] + C51 * K11 + C52 * K21 + C53 * K31 + C54 * K41 + bfhi(b1p[mb * 2 + 0]));
            float h2 = tanh_fast(Py[i + 2] + C51 * K12 + C52 * K22 + C53 * K32 + C54 * K42 + bflo(b1p[mb * 2 + 1]));
            float h3 = tanh_fast(Py[i + 3] + C51 * K13 + C52 * K23 + C53 * K33 + C54 * K43 + bfhi(b1p[mb * 2 + 1]));
            u32x2 w; w.x = pk(h0, h1); w.y = pk(h2, h3);
            *(u32x2*)(wrC + nb * 16 * HSTR + mb * 16) = w;
            float part = h0 * w2fv[mb * 4 + 0] + h1 * w2fv[mb * 4 + 1] +
                         h2 * w2fv[mb * 4 + 2] + h3 * w2fv[mb * 4 + 3];
            if (nb == 0) ts0 += part; else ts1 += part;
            st[p]     = pk(D61 * K10 + D62 * K20 + D63 * K30 + D64 * K40,
                           D61 * K11 + D62 * K21 + D63 * K31 + D64 * K41);
            st[p + 1] = pk(D61 * K12 + D62 * K22 + D63 * K32 + D64 * K42,
                           D61 * K13 + D62 * K23 + D63 * K33 + D64 * K43);
            Py[i + 0] += E1 * K10 + E3 * K30 + E4 * K40;
            Py[i + 1] += E1 * K11 + E3 * K31 + E4 * K41;
            Py[i + 2] += E1 * K12 + E3 * K32 + E4 * K42;
            Py[i + 3] += E1 * K13 + E3 * K33 + E4 * K43;
          }
        gp0 += GB5 * ts0; gp1 += GB5 * ts1;
      } else if (s == 5) {
        const float D65 = DT * (float)(-5103.0/18656.0 + 2187.0/6784.0);
        const float E5  = DT * (float)(-2187.0/6784.0);
#pragma unroll
        for (int mb = 0; mb < 4; ++mb)
#pragma unroll
          for (int nb = 0; nb < 2; ++nb) {
            int i = mb * 8 + nb * 4, p = mb * 4 + nb * 2;
            float Ka = acc[mb][nb][0] + bflo(g0p[mb * 2 + 0]);
            float Kb = acc[mb][nb][1] + bfhi(g0p[mb * 2 + 0]);
            float Kc = acc[mb][nb][2] + bflo(g0p[mb * 2 + 1]);
            float Kd = acc[mb][nb][3] + bfhi(g0p[mb * 2 + 1]);
            float h0 = tanh_fast(Py[i + 0] + bflo(st[p])     + D65 * Ka + bflo(b1p[mb * 2 + 0]));
            float h1 = tanh_fast(Py[i + 1] + bfhi(st[p])     + D65 * Kb + bfhi(b1p[mb * 2 + 0]));
            float h2 = tanh_fast(Py[i + 2] + bflo(st[p + 1]) + D65 * Kc + bflo(b1p[mb * 2 + 1]));
            float h3 = tanh_fast(Py[i + 3] + bfhi(st[p + 1]) + D65 * Kd + bfhi(b1p[mb * 2 + 1]));
            u32x2 w; w.x = pk(h0, h1); w.y = pk(h2, h3);
            *(u32x2*)(wrC + nb * 16 * HSTR + mb * 16) = w;
            float part = h0 * w2fv[mb * 4 + 0] + h1 * w2fv[mb * 4 + 1] +
                         h2 * w2fv[mb * 4 + 2] + h3 * w2fv[mb * 4 + 3];
            if (nb == 0) ts0 += part; else ts1 += part;
            Py[i + 0] += E5 * Ka; Py[i + 1] += E5 * Kb;
            Py[i + 2] += E5 * Kc; Py[i + 3] += E5 * Kd;
          }
        gp0 += GB6 * ts0; gp1 += GB6 * ts1;
      } else {   // s == 6: finish step, emit h1 of next step
        const float E6 = DT * (float)(11.0/84.0);
#pragma unroll
        for (int mb = 0; mb < 4; ++mb)
#pragma unroll
          for (int nb = 0; nb < 2; ++nb) {
            int i = mb * 8 + nb * 4;
            Py[i + 0] += E6 * (acc[mb][nb][0] + bflo(g0p[mb * 2 + 0]));
            Py[i + 1] += E6 * (acc[mb][nb][1] + bfhi(g0p[mb * 2 + 0]));
            Py[i + 2] += E6 * (acc[mb][nb][2] + bflo(g0p[mb * 2 + 1]));
            Py[i + 3] += E6 * (acc[mb][nb][3] + bfhi(g0p[mb * 2 + 1]));
            float h0 = tanh_fast(Py[i + 0] + bflo(b1p[mb * 2 + 0]));
            float h1 = tanh_fast(Py[i + 1] + bfhi(b1p[mb * 2 + 0]));
            float h2 = tanh_fast(Py[i + 2] + bflo(b1p[mb * 2 + 1]));
            float h3 = tanh_fast(Py[i + 3] + bfhi(b1p[mb * 2 + 1]));
            u32x2 w; w.x = pk(h0, h1); w.y = pk(h2, h3);
            *(u32x2*)(wrC + nb * 16 * HSTR + mb * 16) = w;
            float part = h0 * w2fv[mb * 4 + 0] + h1 * w2fv[mb * 4 + 1] +
                         h2 * w2fv[mb * 4 + 2] + h3 * w2fv[mb * 4 + 3];
            if (nb == 0) ts0 += part; else ts1 += part;
          }
        if (step != 15) { gp0 += GB1 * ts0; gp1 += GB1 * ts1; }  // h1 of step+1
      }
      bar_lds();   // h_{s+1} visible; aP prefetch stays in flight
      { const u16* t = rdC; rdC = rdO; rdO = t; }
      { u16* t = wrC; wrC = wrO; wrO = t; }
    } // stages
  } // steps

  // ---- out[row] = f0 + sum(gp) + b2f + bfc ----
  {
    float* redf = (float*)lds;   // last bar_lds drained all h readers
    float p0 = gp0, p1 = gp1;
    p0 += __shfl_xor(p0, 16); p0 += __shfl_xor(p0, 32);
    p1 += __shfl_xor(p1, 16); p1 += __shfl_xor(p1, 32);
    if (laneq == 0) {
      redf[(0 * 16 + lanel) * 8 + wv] = p0;
      redf[(1 * 16 + lanel) * 8 + wv] = p1;
    }
    __syncthreads();
    if (tid < MTILE) {
      float s = f0[wg * MTILE + tid] + b2f[0] + bfc[0];
#pragma unroll
      for (int w = 0; w < 8; ++w) s += redf[tid * 8 + w];
      out[wg * MTILE + tid] = s;
    }
  }
}

extern "C" void kernel_launch(void* const* d_in, const int* in_sizes, int n_in,
                              void* d_out, int out_size, void* d_ws, size_t ws_size,
                              hipStream_t stream) {
  const float* x   = (const float*)d_in[0];
  const float* W1  = (const float*)d_in[1];
  const float* b1  = (const float*)d_in[2];
  const float* W2  = (const float*)d_in[3];
  const float* b2  = (const float*)d_in[4];
  const float* wfc = (const float*)d_in[5];
  const float* bfc = (const float*)d_in[6];
  float* out = (float*)d_out;

  u16*   w1t = (u16*)d_ws;                 // [512][256] bf16  (256 KB)
  u16*   gt  = w1t + DIMH * DIMD;          // [512][512] bf16  (512 KB)
  float* g0  = (float*)(gt + DIMH * DIMH); // [512] f32
  float* w2f = g0 + DIMH;                  // [512] f32
  float* b2f = w2f + DIMH;                 // [1] f32 (+pad)
  float* f0  = b2f + 4;                    // [16384] f32

  hipLaunchKernelGGL(convert_w1, dim3(512),  dim3(256), 0, stream, W1, w1t);
  hipLaunchKernelGGL(make_gt,    dim3(1024), dim3(256), 0, stream, W1, W2, gt);
  hipLaunchKernelGGL(make_aux,   dim3(1),    dim3(512), 0, stream, W1, W2, b2, wfc, g0, w2f, b2f);
  hipLaunchKernelGGL(make_f0,    dim3(4096), dim3(256), 0, stream, x, wfc, f0);
  hipLaunchKernelGGL(ode_fused,  dim3(16384 / MTILE), dim3(NTHREADS), 0, stream,
                     x, b1, bfc, w1t, gt, g0, w2f, b2f, f0, out);
}

// Round 9
// 1621.261 us; speedup vs baseline: 2.1811x; 2.1811x over previous
//
#include <hip/hip_runtime.h>

typedef unsigned short u16;
typedef unsigned int   u32;
typedef __bf16 bf16x8 __attribute__((ext_vector_type(8)));
typedef float  f32x4  __attribute__((ext_vector_type(4)));
typedef u32    u32x2  __attribute__((ext_vector_type(2)));

#define DIMD  256
#define DIMH  512
#define MTILE 64
#define NTHREADS 512

// LDS (u16 units). Row strides padded +16B (keeps b128 alignment).
#define USTR 264
#define HSTR 520
#define U_BASE 0
#define H_BASE (MTILE*USTR)             // 16896
#define LDS_U16 (H_BASE + MTILE*HSTR)   // 50176 u16 = 100352 B

#define DT 0.0625f

__device__ __forceinline__ u16 f2bf(float f) {          // RNE fp32->bf16
  u32 u = __float_as_uint(f);
  u += 0x7FFFu + ((u >> 16) & 1u);
  return (u16)(u >> 16);
}
__device__ __forceinline__ u32 pk(float a, float b) {
#if __has_builtin(__builtin_amdgcn_cvt_pk_bf16_f32)
  auto v = __builtin_amdgcn_cvt_pk_bf16_f32(a, b);      // v_cvt_pk_bf16_f32 (RNE)
  u32 r; __builtin_memcpy(&r, &v, 4); return r;
#else
  return (u32)f2bf(a) | ((u32)f2bf(b) << 16);
#endif
}
__device__ __forceinline__ float bflo(u32 p) { return __uint_as_float(p << 16); }
__device__ __forceinline__ float bfhi(u32 p) { return __uint_as_float(p & 0xFFFF0000u); }
__device__ __forceinline__ float tanh_fast(float x) {
  float e = __builtin_amdgcn_exp2f(x * 2.8853900817779268f);  // 2*log2(e)
  return 1.0f - 2.0f * __builtin_amdgcn_rcpf(e + 1.0f);
}

// Barrier that drains ONLY LDS ops (lgkmcnt). __syncthreads() emits
// s_waitcnt vmcnt(0) lgkmcnt(0) which drains our in-flight global weight
// prefetches (the m97-class ~20% stall). Barrier correctness here needs only
// LDS visibility: weights are read-only, global stores happen only at exit.
// 0xC07F = vmcnt(63) expcnt(7) lgkmcnt(0) in gfx9-family encoding.
__device__ __forceinline__ void bar_lds() {
  asm volatile("" ::: "memory");
  __builtin_amdgcn_s_waitcnt(0xC07F);
  __builtin_amdgcn_s_barrier();
  asm volatile("" ::: "memory");
}

// W1[256][512] -> W1T bf16 [hcol=512][k=256]; W2[512][256] -> W2T bf16 [dcol=256][k=512]
__global__ void convert_w(const float* __restrict__ W1, const float* __restrict__ W2,
                          u16* __restrict__ w1t, u16* __restrict__ w2t) {
  int idx = blockIdx.x * 256 + threadIdx.x;
  {
    int n = idx >> 8, k = idx & 255;
    w1t[idx] = f2bf(W1[k * DIMH + n]);
  }
  {
    int n = idx >> 9, k = idx & 511;
    w2t[idx] = f2bf(W2[k * DIMD + n]);
  }
}

__device__ __forceinline__ void mfma_16(f32x4 (&acc)[4][4],
                                        const bf16x8 (&a)[4], const bf16x8 (&b)[4]) {
#pragma unroll
  for (int mb = 0; mb < 4; ++mb)
#pragma unroll
    for (int nb = 0; nb < 4; ++nb)
      acc[mb][nb] = __builtin_amdgcn_mfma_f32_16x16x32_bf16(a[mb], b[nb], acc[mb][nb], 0, 0, 0);
}
__device__ __forceinline__ void mfma_8(f32x4 (&acc)[2][4],
                                       const bf16x8 (&a)[2], const bf16x8 (&b)[4]) {
#pragma unroll
  for (int mb = 0; mb < 2; ++mb)
#pragma unroll
    for (int nb = 0; nb < 4; ++nb)
      acc[mb][nb] = __builtin_amdgcn_mfma_f32_16x16x32_bf16(a[mb], b[nb], acc[mb][nb], 0, 0, 0);
}

// TERMINAL KERNEL (best measured: 1605.6 us). Structure: 1 WG/CU, 8 waves,
// 2 waves/SIMD, 128 VGPR + ~96 AGPR = the register-feasibility boundary of
// this decomposition. Measured across 8 rounds: ANY added per-thread state
// (deeper prefetch, more waves, dual pipelines, P-space restructure) spills
// (FETCH_SIZE explodes to GBs); register-neutral rescheduling is neutral.
// The ~50% stall is L2/LDS latency per K-halfstep covered by only 2 lockstep
// waves -- fixable only with registers or waves, both exhausted.
__global__ __attribute__((amdgpu_flat_work_group_size(NTHREADS, NTHREADS),
                          amdgpu_waves_per_eu(2, 2)))
void ode_fused(
    const float* __restrict__ x,   const float* __restrict__ b1,
    const float* __restrict__ b2,  const float* __restrict__ wfc,
    const float* __restrict__ bfc, const u16* __restrict__ w1t,
    const u16* __restrict__ w2t,   float* __restrict__ out)
{
  __shared__ u16 lds[LDS_U16];
  __shared__ u32 k2f[16 * NTHREADS];     // parked k2 ([j][tid]: conflict-free)

  const int tid   = threadIdx.x;
  const int wg    = blockIdx.x;
  const int wv    = tid >> 6;          // wave 0..7
  const int lane  = tid & 63;
  const int lanel = lane & 15;
  const int laneq = lane >> 4;

  // Per-thread LDS base pointers (all tile accesses become base + imm offset)
  const u16* uRd = &lds[U_BASE + lanel * USTR + laneq * 8];
  const u16* hRd = &lds[H_BASE + lanel * HSTR + laneq * 8];
  u16* uWr = &lds[U_BASE + lanel * USTR + wv * 32 + laneq * 4];
  u16* hWr = &lds[H_BASE + lanel * HSTR + wv * 64 + laneq * 4];

  // Thread's owned positions (= its GEMM2 C/D fragment):
  //   rows:  nb*16 + lanel               (nb 0..3)
  //   dcols: wv*32 + mb*16 + laneq*4 + r (mb 0..1, r 0..3)
  // flat index i = nb*8 + mb*4 + r ; packed pair p = nb*4 + mb*2 + (r>>1)

  u32 b1p[8], b2p[4];
#pragma unroll
  for (int mb = 0; mb < 4; ++mb) {
    int base = wv * 64 + mb * 16 + laneq * 4;
    b1p[mb * 2 + 0] = pk(b1[base + 0], b1[base + 1]);
    b1p[mb * 2 + 1] = pk(b1[base + 2], b1[base + 3]);
  }
#pragma unroll
  for (int mb = 0; mb < 2; ++mb) {
    int base = wv * 32 + mb * 16 + laneq * 4;
    b2p[mb * 2 + 0] = pk(b2[base + 0], b2[base + 1]);
    b2p[mb * 2 + 1] = pk(b2[base + 2], b2[base + 3]);
  }

  // y in fp32 registers (precision anchor)
  float yv[32];
#pragma unroll
  for (int nb = 0; nb < 4; ++nb)
#pragma unroll
    for (int mb = 0; mb < 2; ++mb) {
      const float4 v = *(const float4*)&x[(wg * 64 + nb * 16 + lanel) * DIMD +
                                          wv * 32 + mb * 16 + laneq * 4];
      int i = nb * 8 + mb * 4;
      yv[i + 0] = v.x; yv[i + 1] = v.y; yv[i + 2] = v.z; yv[i + 3] = v.w;
    }

  // write u1 = bf16(y)
#pragma unroll
  for (int nb = 0; nb < 4; ++nb)
#pragma unroll
    for (int mb = 0; mb < 2; ++mb) {
      int i = nb * 8 + mb * 4;
      u32x2 w; w.x = pk(yv[i], yv[i + 1]); w.y = pk(yv[i + 2], yv[i + 3]);
      *(u32x2*)(uWr + nb * 16 * USTR + mb * 16) = w;
    }

  const u16* w1base[4];
#pragma unroll
  for (int mb = 0; mb < 4; ++mb)
    w1base[mb] = w1t + (wv * 64 + mb * 16 + lanel) * DIMD + laneq * 8;
  const u16* w2base[2];
#pragma unroll
  for (int mb = 0; mb < 2; ++mb)
    w2base[mb] = w2t + (wv * 32 + mb * 16 + lanel) * DIMH + laneq * 8;

  auto ldA1 = [&](bf16x8 (&a)[4], int kk) {
#pragma unroll
    for (int mb = 0; mb < 4; ++mb) a[mb] = *(const bf16x8*)(w1base[mb] + kk * 32);
  };
  auto ldB1 = [&](bf16x8 (&b)[4], int kk) {
#pragma unroll
    for (int nb = 0; nb < 4; ++nb) b[nb] = *(const bf16x8*)(uRd + nb * 16 * USTR + kk * 32);
  };
  auto ldA2 = [&](bf16x8 (&a)[2], int kk) {
#pragma unroll
    for (int mb = 0; mb < 2; ++mb) a[mb] = *(const bf16x8*)(w2base[mb] + kk * 32);
  };
  auto ldB2 = [&](bf16x8 (&b)[4], int kk) {
#pragma unroll
    for (int nb = 0; nb < 4; ++nb) b[nb] = *(const bf16x8*)(hRd + nb * 16 * HSTR + kk * 32);
  };

  // Loop-carried k-state (32 u32):
  //   st[0:16)  = k1 packed (s1..s4), then u6d packed (s4..s5)
  //   st[16:32) = k3 packed (s3..s4)
  //   k2 packed lives in k2f (LDS)
  u32 st[32];

  bf16x8 aP1[4];          // GEMM1 kk=0 weight frags, prefetched across barrier
  ldA1(aP1, 0);
  bar_lds();              // u1 visible; weight prefetch stays in flight

#pragma unroll 1
  for (int step = 0; step < 16; ++step) {
#pragma unroll 1
    for (int s = 1; s <= 6; ++s) {
      // ---------- GEMM1': D[hcol][row] = W1T(A,global) x u(B,LDS) ----------
      f32x4 acc[4][4];
#pragma unroll
      for (int mb = 0; mb < 4; ++mb)
#pragma unroll
        for (int nb = 0; nb < 4; ++nb) acc[mb][nb] = (f32x4){0.f, 0.f, 0.f, 0.f};
      bf16x8 aA[4], bA[4], aB[4], bB[4];
#pragma unroll
      for (int mb = 0; mb < 4; ++mb) aA[mb] = aP1[mb];
      ldB1(bA, 0);
#pragma unroll 1
      for (int kk2 = 0; kk2 < 3; ++kk2) {
        ldA1(aB, 2 * kk2 + 1); ldB1(bB, 2 * kk2 + 1);
        mfma_16(acc, aA, bA);
        ldA1(aA, 2 * kk2 + 2); ldB1(bA, 2 * kk2 + 2);
        mfma_16(acc, aB, bB);
      }
      ldA1(aB, 7); ldB1(bB, 7);
      mfma_16(acc, aA, bA);
      bf16x8 aP2[2];
      ldA2(aP2, 0);                   // GEMM2 kk=0 weight prefetch
      mfma_16(acc, aB, bB);

      // epilogue1: h = tanh(acc + b1)
#pragma unroll
      for (int mb = 0; mb < 4; ++mb)
#pragma unroll
        for (int nb = 0; nb < 4; ++nb) {
          float h0 = tanh_fast(acc[mb][nb][0] + bflo(b1p[mb * 2 + 0]));
          float h1 = tanh_fast(acc[mb][nb][1] + bfhi(b1p[mb * 2 + 0]));
          float h2 = tanh_fast(acc[mb][nb][2] + bflo(b1p[mb * 2 + 1]));
          float h3 = tanh_fast(acc[mb][nb][3] + bfhi(b1p[mb * 2 + 1]));
          u32x2 w; w.x = pk(h0, h1); w.y = pk(h2, h3);
          *(u32x2*)(hWr + nb * 16 * HSTR + mb * 16) = w;
        }
      bar_lds();   // h visible; aP2 stays in flight

      // ---------- GEMM2': D[dcol][row] = W2T(A,global) x h(B,LDS) ----------
      f32x4 acc2[2][4];
#pragma unroll
      for (int mb = 0; mb < 2; ++mb)
#pragma unroll
        for (int nb = 0; nb < 4; ++nb) acc2[mb][nb] = (f32x4){0.f, 0.f, 0.f, 0.f};
      bf16x8 cA[2], dA[4], cB[2], dB[4];
#pragma unroll
      for (int mb = 0; mb < 2; ++mb) cA[mb] = aP2[mb];
      ldB2(dA, 0);
#pragma unroll 1
      for (int kk2 = 0; kk2 < 7; ++kk2) {
        ldA2(cB, 2 * kk2 + 1); ldB2(dB, 2 * kk2 + 1);
        mfma_8(acc2, cA, dA);
        ldA2(cA, 2 * kk2 + 2); ldB2(dA, 2 * kk2 + 2);
        mfma_8(acc2, cB, dB);
      }
      ldA2(cB, 15); ldB2(dB, 15);
      mfma_8(acc2, cA, dA);
      ldA1(aP1, 0);                   // next-stage GEMM1 kk=0 weight prefetch
      mfma_8(acc2, cB, dB);

      // ---------- fused epilogue2 + stage epilogue ----------
      if (s == 1) {
        const float C = DT * 0.2f;
#pragma unroll
        for (int mb = 0; mb < 2; ++mb)
#pragma unroll
          for (int nb = 0; nb < 4; ++nb) {
            int i = nb * 8 + mb * 4, p = nb * 4 + mb * 2;
            float k0 = acc2[mb][nb][0] + bflo(b2p[mb * 2 + 0]);
            float k1 = acc2[mb][nb][1] + bfhi(b2p[mb * 2 + 0]);
            float k2 = acc2[mb][nb][2] + bflo(b2p[mb * 2 + 1]);
            float k3 = acc2[mb][nb][3] + bfhi(b2p[mb * 2 + 1]);
            st[p] = pk(k0, k1); st[p + 1] = pk(k2, k3);
            u32x2 w;
            w.x = pk(yv[i] + C * k0, yv[i + 1] + C * k1);
            w.y = pk(yv[i + 2] + C * k2, yv[i + 3] + C * k3);
            *(u32x2*)(uWr + nb * 16 * USTR + mb * 16) = w;
          }
      } else if (s == 2) {
        const float C1 = DT * 0.075f, C2 = DT * 0.225f;
#pragma unroll
        for (int mb = 0; mb < 2; ++mb)
#pragma unroll
          for (int nb = 0; nb < 4; ++nb) {
            int i = nb * 8 + mb * 4, p = nb * 4 + mb * 2;
            float k0 = acc2[mb][nb][0] + bflo(b2p[mb * 2 + 0]);
            float k1 = acc2[mb][nb][1] + bfhi(b2p[mb * 2 + 0]);
            float k2 = acc2[mb][nb][2] + bflo(b2p[mb * 2 + 1]);
            float k3 = acc2[mb][nb][3] + bfhi(b2p[mb * 2 + 1]);
            k2f[p * NTHREADS + tid]       = pk(k0, k1);   // park k2 in LDS
            k2f[(p + 1) * NTHREADS + tid] = pk(k2, k3);
            u32x2 w;
            w.x = pk(yv[i]     + C1 * bflo(st[p])     + C2 * k0,
                     yv[i + 1] + C1 * bfhi(st[p])     + C2 * k1);
            w.y = pk(yv[i + 2] + C1 * bflo(st[p + 1]) + C2 * k2,
                     yv[i + 3] + C1 * bfhi(st[p + 1]) + C2 * k3);
            *(u32x2*)(uWr + nb * 16 * USTR + mb * 16) = w;
          }
      } else if (s == 3) {
        const float C1 = DT * (float)(44.0/45.0);
        const float C2 = DT * (float)(-56.0/15.0);
        const float C3 = DT * (float)(32.0/9.0);
#pragma unroll
        for (int mb = 0; mb < 2; ++mb)
#pragma unroll
          for (int nb = 0; nb < 4; ++nb) {
            int i = nb * 8 + mb * 4, p = nb * 4 + mb * 2;
            float k0 = acc2[mb][nb][0] + bflo(b2p[mb * 2 + 0]);
            float k1 = acc2[mb][nb][1] + bfhi(b2p[mb * 2 + 0]);
            float k2 = acc2[mb][nb][2] + bflo(b2p[mb * 2 + 1]);
            float k3 = acc2[mb][nb][3] + bfhi(b2p[mb * 2 + 1]);
            st[16 + p] = pk(k0, k1); st[16 + p + 1] = pk(k2, k3);
            u32 q0 = k2f[p * NTHREADS + tid], q1 = k2f[(p + 1) * NTHREADS + tid];
            u32x2 w;
            w.x = pk(yv[i]     + C1 * bflo(st[p])     + C2 * bflo(q0) + C3 * k0,
                     yv[i + 1] + C1 * bfhi(st[p])     + C2 * bfhi(q0) + C3 * k1);
            w.y = pk(yv[i + 2] + C1 * bflo(st[p + 1]) + C2 * bflo(q1) + C3 * k2,
                     yv[i + 3] + C1 * bfhi(st[p + 1]) + C2 * bfhi(q1) + C3 * k3);
            *(u32x2*)(uWr + nb * 16 * USTR + mb * 16) = w;
          }
      } else if (s == 4) {
        // u5; fold k1..k4 into u6-delta and y; k1..k3 die here
        const float C51 = DT * (float)(19372.0/6561.0);
        const float C52 = DT * (float)(-25360.0/2187.0);
        const float C53 = DT * (float)(64448.0/6561.0);
        const float C54 = DT * (float)(-212.0/729.0);
        const float D61 = DT * (float)(9017.0/3168.0  - 35.0/384.0);   // A61-B1
        const float D62 = DT * (float)(-355.0/33.0);                   // A62 (B2=0)
        const float D63 = DT * (float)(46732.0/5247.0 - 500.0/1113.0); // A63-B3
        const float D64 = DT * (float)(49.0/176.0     - 125.0/192.0);  // A64-B4
        const float E1  = DT * (float)(35.0/384.0);
        const float E3  = DT * (float)(500.0/1113.0);
        const float E4  = DT * (float)(125.0/192.0);
#pragma unroll
        for (int mb = 0; mb < 2; ++mb)
#pragma unroll
          for (int nb = 0; nb < 4; ++nb) {
            int i = nb * 8 + mb * 4, p = nb * 4 + mb * 2;
            float k40 = acc2[mb][nb][0] + bflo(b2p[mb * 2 + 0]);
            float k41 = acc2[mb][nb][1] + bfhi(b2p[mb * 2 + 0]);
            float k42 = acc2[mb][nb][2] + bflo(b2p[mb * 2 + 1]);
            float k43 = acc2[mb][nb][3] + bfhi(b2p[mb * 2 + 1]);
            float k10 = bflo(st[p]),      k11 = bfhi(st[p]);
            float k12 = bflo(st[p + 1]),  k13 = bfhi(st[p + 1]);
            u32 q0 = k2f[p * NTHREADS + tid], q1 = k2f[(p + 1) * NTHREADS + tid];
            float k20 = bflo(q0), k21 = bfhi(q0);
            float k22 = bflo(q1), k23 = bfhi(q1);
            float k30 = bflo(st[16 + p]),     k31 = bfhi(st[16 + p]);
            float k32 = bflo(st[16 + p + 1]), k33 = bfhi(st[16 + p + 1]);
            u32x2 w;
            w.x = pk(yv[i]     + C51 * k10 + C52 * k20 + C53 * k30 + C54 * k40,
                     yv[i + 1] + C51 * k11 + C52 * k21 + C53 * k31 + C54 * k41);
            w.y = pk(yv[i + 2] + C51 * k12 + C52 * k22 + C53 * k32 + C54 * k42,
                     yv[i + 3] + C51 * k13 + C52 * k23 + C53 * k33 + C54 * k43);
            *(u32x2*)(uWr + nb * 16 * USTR + mb * 16) = w;
            st[p]     = pk(D61 * k10 + D62 * k20 + D63 * k30 + D64 * k40,
                           D61 * k11 + D62 * k21 + D63 * k31 + D64 * k41);
            st[p + 1] = pk(D61 * k12 + D62 * k22 + D63 * k32 + D64 * k42,
                           D61 * k13 + D62 * k23 + D63 * k33 + D64 * k43);
            yv[i]     += E1 * k10 + E3 * k30 + E4 * k40;
            yv[i + 1] += E1 * k11 + E3 * k31 + E4 * k41;
            yv[i + 2] += E1 * k12 + E3 * k32 + E4 * k42;
            yv[i + 3] += E1 * k13 + E3 * k33 + E4 * k43;
          }
      } else if (s == 5) {
        const float D65 = DT * (float)(-5103.0/18656.0 + 2187.0/6784.0); // A65-B5
        const float E5  = DT * (float)(-2187.0/6784.0);
#pragma unroll
        for (int mb = 0; mb < 2; ++mb)
#pragma unroll
          for (int nb = 0; nb < 4; ++nb) {
            int i = nb * 8 + mb * 4, p = nb * 4 + mb * 2;
            float k0 = acc2[mb][nb][0] + bflo(b2p[mb * 2 + 0]);
            float k1 = acc2[mb][nb][1] + bfhi(b2p[mb * 2 + 0]);
            float k2 = acc2[mb][nb][2] + bflo(b2p[mb * 2 + 1]);
            float k3 = acc2[mb][nb][3] + bfhi(b2p[mb * 2 + 1]);
            u32x2 w;
            w.x = pk(yv[i]     + bflo(st[p])     + D65 * k0,
                     yv[i + 1] + bfhi(st[p])     + D65 * k1);
            w.y = pk(yv[i + 2] + bflo(st[p + 1]) + D65 * k2,
                     yv[i + 3] + bfhi(st[p + 1]) + D65 * k3);
            *(u32x2*)(uWr + nb * 16 * USTR + mb * 16) = w;
            yv[i]     += E5 * k0;
            yv[i + 1] += E5 * k1;
            yv[i + 2] += E5 * k2;
            yv[i + 3] += E5 * k3;
          }
      } else {
        const float E6 = DT * (float)(11.0/84.0);
#pragma unroll
        for (int mb = 0; mb < 2; ++mb)
#pragma unroll
          for (int nb = 0; nb < 4; ++nb) {
            int i = nb * 8 + mb * 4;
            yv[i]     += E6 * (acc2[mb][nb][0] + bflo(b2p[mb * 2 + 0]));
            yv[i + 1] += E6 * (acc2[mb][nb][1] + bfhi(b2p[mb * 2 + 0]));
            yv[i + 2] += E6 * (acc2[mb][nb][2] + bflo(b2p[mb * 2 + 1]));
            yv[i + 3] += E6 * (acc2[mb][nb][3] + bfhi(b2p[mb * 2 + 1]));
            u32x2 w;
            w.x = pk(yv[i], yv[i + 1]); w.y = pk(yv[i + 2], yv[i + 3]);
            *(u32x2*)(uWr + nb * 16 * USTR + mb * 16) = w;
          }
      }
      bar_lds();   // u visible; aP1 prefetch stays in flight
    } // stages
  } // steps

  // ---- out[row] = y . Wfc + bfc ----
  {
    float wfcv[8];
#pragma unroll
    for (int mb = 0; mb < 2; ++mb)
#pragma unroll
      for (int r = 0; r < 4; ++r)
        wfcv[mb * 4 + r] = wfc[wv * 32 + mb * 16 + laneq * 4 + r];
    float* redf = (float*)lds;   // safe: last bar_lds drained all U/H readers
    float pr[4];
#pragma unroll
    for (int nb = 0; nb < 4; ++nb) {
      float p = 0.f;
#pragma unroll
      for (int mb = 0; mb < 2; ++mb)
#pragma unroll
        for (int r = 0; r < 4; ++r)
          p += yv[nb * 8 + mb * 4 + r] * wfcv[mb * 4 + r];
      p += __shfl_xor(p, 16);
      p += __shfl_xor(p, 32);
      pr[nb] = p;
    }
    if (laneq == 0) {
#pragma unroll
      for (int nb = 0; nb < 4; ++nb)
        redf[(nb * 16 + lanel) * 8 + wv] = pr[nb];
    }
    __syncthreads();
    if (tid < 64) {
      float s = bfc[0];
#pragma unroll
      for (int w = 0; w < 8; ++w) s += redf[tid * 8 + w];
      out[wg * 64 + tid] = s;
    }
  }
}

extern "C" void kernel_launch(void* const* d_in, const int* in_sizes, int n_in,
                              void* d_out, int out_size, void* d_ws, size_t ws_size,
                              hipStream_t stream) {
  const float* x   = (const float*)d_in[0];
  const float* W1  = (const float*)d_in[1];
  const float* b1  = (const float*)d_in[2];
  const float* W2  = (const float*)d_in[3];
  const float* b2  = (const float*)d_in[4];
  const float* wfc = (const float*)d_in[5];
  const float* bfc = (const float*)d_in[6];
  float* out = (float*)d_out;

  u16* w1t = (u16*)d_ws;                 // [512][256] bf16
  u16* w2t = w1t + DIMH * DIMD;          // [256][512] bf16

  hipLaunchKernelGGL(convert_w, dim3(512), dim3(256), 0, stream, W1, W2, w1t, w2t);
  hipLaunchKernelGGL(ode_fused, dim3(16384 / MTILE), dim3(NTHREADS), 0, stream,
                     x, b1, b2, wfc, bfc, w1t, w2t, out);
}